// Round 4
// baseline (2421.045 us; speedup 1.0000x reference)
//
#include <hip/hip_runtime.h>
#include <hip/hip_bf16.h>

#define NB 512
#define NL 160
#define ND 350

// ---------------- wave (64-lane) reductions ----------------
__device__ __forceinline__ float wsum(float v){
#pragma unroll
  for (int o = 32; o; o >>= 1) v += __shfl_xor(v, o, 64);
  return v;
}
__device__ __forceinline__ float wmaxf(float v){
#pragma unroll
  for (int o = 32; o; o >>= 1) v = fmaxf(v, __shfl_xor(v, o, 64));
  return v;
}
__device__ __forceinline__ unsigned long long wmax64(unsigned long long v){
#pragma unroll
  for (int o = 32; o; o >>= 1){
    unsigned long long u = __shfl_xor(v, o, 64);
    v = (u > v) ? u : v;
  }
  return v;
}

// ---- embedding fetch helper: vec[l][b][d] gathered from tables -------------
__device__ __forceinline__ float emb_at(const float* __restrict__ wemb,
                                        const float* __restrict__ aemb,
                                        int attr_id, int tok_id, int d){
  return (d < 50) ? aemb[attr_id * 50 + d]
                  : wemb[(size_t)tok_id * 300 + (d - 50)];
}

// ---------------- 1. att[b] = Lv_b @ Rv_b^T, masked; att and attT ----------
// One block per batch (global b = b0 + blockIdx.x); gathers embeddings.
// Local chunk layout: att[(bl*160 + l)*160 + r], attT[(bl*160 + r)*160 + l].
__global__ __launch_bounds__(256) void att_gemm(
    const int* __restrict__ l_tok, const int* __restrict__ l_att,
    const int* __restrict__ r_tok, const int* __restrict__ r_att,
    const float* __restrict__ wemb, const float* __restrict__ aemb,
    const int* __restrict__ llen, const int* __restrict__ rlen,
    float* __restrict__ att, float* __restrict__ attT, int b0){
  __shared__ float Lt[160][35];
  __shared__ float Rt[160][35];
  __shared__ float Tb[16][164];   // padded stride
  __shared__ int ltk[160], lat[160], rtk[160], rat[160];
  int bl = blockIdx.x;
  int b  = b0 + bl;
  int tid = threadIdx.x;
  int tx = tid & 15, ty = tid >> 4;

  for (int i = tid; i < 160; i += 256){
    ltk[i] = l_tok[i * NB + b];
    lat[i] = l_att[i * NB + b];
    rtk[i] = r_tok[i * NB + b];
    rat[i] = r_att[i * NB + b];
  }
  __syncthreads();

  float acc[10][10];
#pragma unroll
  for (int i = 0; i < 10; ++i)
#pragma unroll
    for (int j = 0; j < 10; ++j) acc[i][j] = 0.f;

  for (int kc = 0; kc < 350; kc += 35){
    for (int i = tid; i < 160 * 35; i += 256){
      int l = i / 35, dd = i - l * 35;
      int d = kc + dd;
      Lt[l][dd] = emb_at(wemb, aemb, lat[l], ltk[l], d);
      Rt[l][dd] = emb_at(wemb, aemb, rat[l], rtk[l], d);
    }
    __syncthreads();
#pragma unroll 1
    for (int dd = 0; dd < 35; ++dd){
      float La[10], Rb[10];
#pragma unroll
      for (int i = 0; i < 10; ++i) La[i] = Lt[ty + 16 * i][dd];
#pragma unroll
      for (int j = 0; j < 10; ++j) Rb[j] = Rt[tx + 16 * j][dd];
#pragma unroll
      for (int i = 0; i < 10; ++i)
#pragma unroll
        for (int j = 0; j < 10; ++j)
          acc[i][j] = fmaf(La[i], Rb[j], acc[i][j]);
    }
    __syncthreads();
  }

  int ll = llen[b], rl = rlen[b];
#pragma unroll
  for (int i = 0; i < 10; ++i){
    bool lok = (ty + 16 * i) < ll;
#pragma unroll
    for (int j = 0; j < 10; ++j){
      if (!(lok && ((tx + 16 * j) < rl))) acc[i][j] = 0.f;
    }
  }
  // row-major store: att[bl][l][r]
#pragma unroll
  for (int i = 0; i < 10; ++i){
    size_t rowb = ((size_t)bl * 160 + ty + 16 * i) * 160;
#pragma unroll
    for (int j = 0; j < 10; ++j) att[rowb + tx + 16 * j] = acc[i][j];
  }
  // transposed store via LDS
  for (int jj = 0; jj < 10; ++jj){
    __syncthreads();
#pragma unroll
    for (int i = 0; i < 10; ++i) Tb[tx][ty + 16 * i] = acc[i][jj];
    __syncthreads();
    for (int i2 = tid; i2 < 16 * 160; i2 += 256){
      int rloc = i2 / 160, l = i2 - rloc * 160;
      attT[((size_t)bl * 160 + 16 * jj + rloc) * 160 + l] = Tb[rloc][l];
    }
  }
}

// ---------------- 2. per-row softmax+renorm, w, top-3, counter, |diff| ------
// attR rows contiguous over kv. outC[(q*CB + bl)*ND + d]. One wave per row.
__global__ __launch_bounds__(256) void proc_kernel(
    const float* __restrict__ attR,
    const int* __restrict__ ownLen, const int* __restrict__ kvLen,
    const int* __restrict__ ownTok, const int* __restrict__ ownAttr,
    const int* __restrict__ kvTok,  const int* __restrict__ kvAttr,
    const float* __restrict__ wemb, const float* __restrict__ aemb,
    float* __restrict__ outC, int CB, int b0){
  int lane = threadIdx.x & 63;
  int wid = blockIdx.x * 4 + (threadIdx.x >> 6);
  int q  = wid / CB;
  int bl = wid - q * CB;
  int b  = b0 + bl;
  int nOwn = ownLen[b], nKv = kvLen[b];
  const float* __restrict__ row = attR + ((size_t)bl * 160 + q) * 160;
  int rr0 = lane, rr1 = lane + 64, rr2 = lane + 128;
  bool has2 = rr2 < 160;
  float a0 = row[rr0];
  float a1 = row[rr1];
  float a2 = has2 ? row[rr2] : 0.f;
  float v0 = (rr0 < nKv) ? a0 : -10.f;
  float v1 = (rr1 < nKv) ? a1 : -10.f;
  float v2 = has2 ? ((rr2 < nKv) ? a2 : -10.f) : -1e30f;
  float m = wmaxf(fmaxf(v0, fmaxf(v1, v2)));
  float e0 = expf(v0 - m);
  float e1 = expf(v1 - m);
  float e2 = has2 ? expf(v2 - m) : 0.f;
  float ssum = wsum(e0 + e1 + e2);
  float p0 = (rr0 < nKv) ? e0 / ssum : 0.f;
  float p1 = (rr1 < nKv) ? e1 / ssum : 0.f;
  float p2 = (has2 && rr2 < nKv) ? e2 / ssum : 0.f;
  float s2 = wsum(p0 + p1 + p2);
  float inv = 1.f / (s2 + 1e-13f);
  p0 *= inv; p1 *= inv; p2 *= inv;
  float sp  = wsum(p0 + p1 + p2);
  float sp2 = wsum(p0 * p0 + p1 * p1 + p2 * p2);
  float kf = (float)nKv;
  float mean = sp / kf;
  float w = (sp2 / kf - mean * mean) / fmaxf(mean, 0.001f);
  // top-3, JAX tie-break (lower index wins ties): key = p_bits ## (~idx)
  unsigned long long key0 = (((unsigned long long)__float_as_uint(p0)) << 32) | (unsigned)(0xFFFFFFFFu - rr0);
  unsigned long long key1 = (((unsigned long long)__float_as_uint(p1)) << 32) | (unsigned)(0xFFFFFFFFu - rr1);
  unsigned long long key2 = has2 ? ((((unsigned long long)__float_as_uint(p2)) << 32) | (unsigned)(0xFFFFFFFFu - rr2)) : 0ull;
  float tv[3]; int ti[3];
#pragma unroll
  for (int kk = 0; kk < 3; ++kk){
    unsigned long long loc = key0 > key1 ? key0 : key1;
    loc = key2 > loc ? key2 : loc;
    unsigned long long g = wmax64(loc);
    tv[kk] = __uint_as_float((unsigned)(g >> 32));
    ti[kk] = (int)(0xFFFFFFFFu - (unsigned)g);
    if (key0 == g) key0 = 0ull;
    if (key1 == g) key1 = 0ull;
    if (key2 == g) key2 = 0ull;
  }
  float tsum = tv[0] + tv[1] + tv[2];
  float ad = 1.f / fmaxf(tsum, 0.001f);
  float c0 = tv[0] * ad, c1 = tv[1] * ad, c2 = tv[2] * ad;
  float* __restrict__ oc = outC + ((size_t)q * CB + bl) * ND;
  if (q < nOwn){
    int oa = ownAttr[q * NB + b],    ot = ownTok[q * NB + b];
    int a0i = kvAttr[ti[0] * NB + b], t0 = kvTok[ti[0] * NB + b];
    int a1i = kvAttr[ti[1] * NB + b], t1 = kvTok[ti[1] * NB + b];
    int a2i = kvAttr[ti[2] * NB + b], t2 = kvTok[ti[2] * NB + b];
    for (int d = lane; d < ND; d += 64){
      float ov = emb_at(wemb, aemb, oa, ot, d);
      float k0 = emb_at(wemb, aemb, a0i, t0, d);
      float k1 = emb_at(wemb, aemb, a1i, t1, d);
      float k2 = emb_at(wemb, aemb, a2i, t2, d);
      float cc = c0 * k0 + c1 * k1 + c2 * k2;
      oc[d] = w * fabsf(ov - cc);
    }
  } else {
    for (int d = lane; d < ND; d += 64) oc[d] = 0.f;
  }
}

// ---------------- 3. pack conv weights into Wcat (600 x 350) ----------------
__global__ __launch_bounds__(256) void wcat_kernel(
    const float* __restrict__ w1, const float* __restrict__ w2,
    const float* __restrict__ w3, float* __restrict__ wcat){
  int idx = blockIdx.x * 256 + threadIdx.x;
  if (idx >= 600 * 350) return;
  int c = idx / 350, d = idx - c * 350;
  float v;
  if (c < 100) v = w1[c * 350 + d];
  else if (c < 300){
    int cc = c - 100; int j = cc / 100; int o = cc - j * 100;
    v = w2[(o * 350 + d) * 2 + j];
  } else {
    int cc = c - 300; int j = cc / 100; int o = cc - j * 100;
    v = w3[(o * 350 + d) * 3 + j];
  }
  wcat[idx] = v;
}

// ---------------- 4. P = X(M x 350) @ Wcat^T(350 x 600) --------------------
__global__ __launch_bounds__(256) void gemm_p(
    const float* __restrict__ A, const float* __restrict__ Wc,
    float* __restrict__ P){
  __shared__ float As[14][132];
  __shared__ float Bs[14][132];
  int m0 = blockIdx.x * 128;
  int n0 = blockIdx.y * 128;
  int tid = threadIdx.x;
  int tx = tid & 15, ty = tid >> 4;
  float acc[8][8];
#pragma unroll
  for (int i = 0; i < 8; ++i)
#pragma unroll
    for (int j = 0; j < 8; ++j) acc[i][j] = 0.f;

  for (int k0 = 0; k0 < 350; k0 += 14){
#pragma unroll
    for (int it = 0; it < 7; ++it){
      int i = tid + it * 256;
      int mm = i / 14, dd = i - mm * 14;
      As[dd][mm] = A[(size_t)(m0 + mm) * 350 + (k0 + dd)];
      int c = n0 + mm;
      Bs[dd][mm] = (c < 600) ? Wc[(size_t)c * 350 + (k0 + dd)] : 0.f;
    }
    __syncthreads();
#pragma unroll 1
    for (int dd = 0; dd < 14; ++dd){
      float a[8], bb[8];
#pragma unroll
      for (int ii = 0; ii < 8; ++ii) a[ii] = As[dd][ty + 16 * ii];
#pragma unroll
      for (int jj = 0; jj < 8; ++jj) bb[jj] = Bs[dd][tx + 16 * jj];
#pragma unroll
      for (int ii = 0; ii < 8; ++ii)
#pragma unroll
        for (int jj = 0; jj < 8; ++jj)
          acc[ii][jj] = fmaf(a[ii], bb[jj], acc[ii][jj]);
    }
    __syncthreads();
  }
#pragma unroll
  for (int ii = 0; ii < 8; ++ii){
    int m = m0 + ty + 16 * ii;
#pragma unroll
    for (int jj = 0; jj < 8; ++jj){
      int c = n0 + tx + 16 * jj;
      if (c < 600) P[(size_t)m * 600 + c] = acc[ii][jj];
    }
  }
}

// ---------------- 5. shift-combine + bias + relu + masked max over t --------
__global__ __launch_bounds__(320) void combine_kernel(
    const float* __restrict__ P, const int* __restrict__ len,
    const float* __restrict__ b1, const float* __restrict__ b2,
    const float* __restrict__ b3, float* __restrict__ feats,
    int sideoff, int CB, int b0){
  int bl = blockIdx.x;
  int b = b0 + bl;
  int c = threadIdx.x;
  if (c >= 300) return;
  int n = len[b];
  float vmax = -1e30f;
  if (c < 100){
    float bias = b1[c];
    for (int t = 0; t < n; ++t){
      float v = P[(size_t)(t * CB + bl) * 600 + c] + bias;
      vmax = fmaxf(vmax, fmaxf(v, 0.f));
    }
  } else if (c < 200){
    int o = c - 100;
    float bias = b2[o];
    for (int t = 0; t + 1 < n; ++t){
      float v = P[(size_t)(t * CB + bl) * 600 + 100 + o]
              + P[(size_t)((t + 1) * CB + bl) * 600 + 200 + o] + bias;
      vmax = fmaxf(vmax, fmaxf(v, 0.f));
    }
  } else {
    int o = c - 200;
    float bias = b3[o];
    for (int t = 0; t + 2 < n; ++t){
      float v = P[(size_t)(t * CB + bl) * 600 + 300 + o]
              + P[(size_t)((t + 1) * CB + bl) * 600 + 400 + o]
              + P[(size_t)((t + 2) * CB + bl) * 600 + 500 + o] + bias;
      vmax = fmaxf(vmax, fmaxf(v, 0.f));
    }
  }
  feats[(size_t)b * 600 + sideoff + c] = vmax;
}

// ---------------- 6. dense head ---------------------------------------------
__global__ __launch_bounds__(64) void dense_kernel(
    const float* __restrict__ feats,
    const float* __restrict__ w1, const float* __restrict__ b1,
    const float* __restrict__ w2, const float* __restrict__ b2,
    float* __restrict__ out){
  __shared__ float fs[600];
  __shared__ float hs[60];
  int b = blockIdx.x, tid = threadIdx.x;
  for (int i = tid; i < 600; i += 64) fs[i] = feats[(size_t)b * 600 + i];
  __syncthreads();
  if (tid < 60){
    float s = b1[tid];
    for (int d = 0; d < 600; ++d) s = fmaf(fs[d], w1[d * 60 + tid], s);
    hs[tid] = fmaxf(s, 0.f);
  }
  __syncthreads();
  if (tid < 2){
    float s = b2[tid];
    for (int j = 0; j < 60; ++j) s = fmaf(hs[j], w2[j * 2 + tid], s);
    out[b * 2 + tid] = s;
  }
}

// ---------------- launch ----------------------------------------------------
extern "C" void kernel_launch(void* const* d_in, const int* in_sizes, int n_in,
                              void* d_out, int out_size, void* d_ws, size_t ws_size,
                              hipStream_t stream){
  const int*   l_tok = (const int*)d_in[0];
  const int*   l_att = (const int*)d_in[1];
  const int*   l_len = (const int*)d_in[2];
  const int*   r_tok = (const int*)d_in[3];
  const int*   r_att = (const int*)d_in[4];
  const int*   r_len = (const int*)d_in[5];
  const float* wemb  = (const float*)d_in[6];
  const float* aemb  = (const float*)d_in[7];
  const float* cw1   = (const float*)d_in[8];
  const float* cb1   = (const float*)d_in[9];
  const float* cw2   = (const float*)d_in[10];
  const float* cb2   = (const float*)d_in[11];
  const float* cw3   = (const float*)d_in[12];
  const float* cb3   = (const float*)d_in[13];
  const float* dw1   = (const float*)d_in[14];
  const float* db1   = (const float*)d_in[15];
  const float* dw2   = (const float*)d_in[16];
  const float* db2   = (const float*)d_in[17];
  float* out = (float*)d_out;
  float* ws  = (float*)d_ws;

  // Pick the largest batch-chunk CB whose workspace footprint fits ws_size.
  // floats needed: persistent (wcat 210000 + feats 307200)
  //              + per-chunk CB*(att 25600 + attT 25600 + lc 56000 + rc 56000 + P 96000)
  // CB must stay a multiple of 4: gemm_p grid.x = 5*CB/4 tiles of 128 rows
  // covers exactly 160*CB rows only when CB % 4 == 0.
  size_t ws_fl = ws_size / sizeof(float);
  int CB = 512;
  while (CB > 4){
    size_t need = (size_t)CB * 259200 + 517200;
    if (need <= ws_fl) break;
    CB >>= 1;
  }

  float* wcat  = ws;                         // 210,000
  float* feats = ws + 210000;                // 307,200
  float* att   = ws + 517200;                // CB*25600
  float* attT  = att  + (size_t)CB * 25600;  // CB*25600
  float* lc    = attT + (size_t)CB * 25600;  // CB*56000
  float* rc    = lc   + (size_t)CB * 56000;  // CB*56000
  float* P     = rc   + (size_t)CB * 56000;  // CB*96000

  wcat_kernel<<<821, 256, 0, stream>>>(cw1, cw2, cw3, wcat);

  int nch = NB / CB;
  dim3 gP(CB * 5 / 4, 5);
  for (int c = 0; c < nch; ++c){
    int b0 = c * CB;
    att_gemm<<<CB, 256, 0, stream>>>(l_tok, l_att, r_tok, r_att, wemb, aemb,
                                     l_len, r_len, att, attT, b0);
    proc_kernel<<<CB * 40, 256, 0, stream>>>(att,  l_len, r_len,
                                             l_tok, l_att, r_tok, r_att,
                                             wemb, aemb, lc, CB, b0);
    proc_kernel<<<CB * 40, 256, 0, stream>>>(attT, r_len, l_len,
                                             r_tok, r_att, l_tok, l_att,
                                             wemb, aemb, rc, CB, b0);
    gemm_p<<<gP, 256, 0, stream>>>(lc, wcat, P);
    combine_kernel<<<CB, 320, 0, stream>>>(P, l_len, cb1, cb2, cb3, feats, 0,   CB, b0);
    gemm_p<<<gP, 256, 0, stream>>>(rc, wcat, P);
    combine_kernel<<<CB, 320, 0, stream>>>(P, r_len, cb1, cb2, cb3, feats, 300, CB, b0);
  }
  dense_kernel<<<NB, 64, 0, stream>>>(feats, dw1, db1, dw2, db2, out);
}

// Round 5
// 1486.017 us; speedup vs baseline: 1.6292x; 1.6292x over previous
//
#include <hip/hip_runtime.h>
#include <hip/hip_bf16.h>

#define NB 512
#define NL 160
#define ND 350

typedef float f32x4 __attribute__((ext_vector_type(4)));
typedef __bf16 bf16x8 __attribute__((ext_vector_type(8)));
typedef unsigned short u16x8 __attribute__((ext_vector_type(8)));

// ---------------- wave (64-lane) reductions ----------------
__device__ __forceinline__ float wsum(float v){
#pragma unroll
  for (int o = 32; o; o >>= 1) v += __shfl_xor(v, o, 64);
  return v;
}
__device__ __forceinline__ float wmaxf(float v){
#pragma unroll
  for (int o = 32; o; o >>= 1) v = fmaxf(v, __shfl_xor(v, o, 64));
  return v;
}
__device__ __forceinline__ unsigned long long wmax64(unsigned long long v){
#pragma unroll
  for (int o = 32; o; o >>= 1){
    unsigned long long u = __shfl_xor(v, o, 64);
    v = (u > v) ? u : v;
  }
  return v;
}

// float -> bf16 bits (RNE), and back
__device__ __forceinline__ unsigned short f2bf(float f){
  unsigned x = __float_as_uint(f);
  unsigned r = (x + 0x7fffu + ((x >> 16) & 1u)) >> 16;
  return (unsigned short)r;
}
__device__ __forceinline__ float bf2f(unsigned short u){
  return __uint_as_float(((unsigned)u) << 16);
}

// ---- embedding fetch helper ------------------------------------------------
__device__ __forceinline__ float emb_at(const float* __restrict__ wemb,
                                        const float* __restrict__ aemb,
                                        int attr_id, int tok_id, int d){
  return (d < 50) ? aemb[attr_id * 50 + d]
                  : wemb[(size_t)tok_id * 300 + (d - 50)];
}

// ---------------- 1. att[b] = Lv_b @ Rv_b^T, masked; att and attT ----------
__global__ __launch_bounds__(256) void att_gemm(
    const int* __restrict__ l_tok, const int* __restrict__ l_att,
    const int* __restrict__ r_tok, const int* __restrict__ r_att,
    const float* __restrict__ wemb, const float* __restrict__ aemb,
    const int* __restrict__ llen, const int* __restrict__ rlen,
    float* __restrict__ att, float* __restrict__ attT, int b0){
  __shared__ float Lt[160][35];
  __shared__ float Rt[160][35];
  __shared__ float Tb[16][164];
  __shared__ int ltk[160], lat[160], rtk[160], rat[160];
  int bl = blockIdx.x;
  int b  = b0 + bl;
  int tid = threadIdx.x;
  int tx = tid & 15, ty = tid >> 4;

  for (int i = tid; i < 160; i += 256){
    ltk[i] = l_tok[i * NB + b];
    lat[i] = l_att[i * NB + b];
    rtk[i] = r_tok[i * NB + b];
    rat[i] = r_att[i * NB + b];
  }
  __syncthreads();

  float acc[10][10];
#pragma unroll
  for (int i = 0; i < 10; ++i)
#pragma unroll
    for (int j = 0; j < 10; ++j) acc[i][j] = 0.f;

  for (int kc = 0; kc < 350; kc += 35){
    for (int i = tid; i < 160 * 35; i += 256){
      int l = i / 35, dd = i - l * 35;
      int d = kc + dd;
      Lt[l][dd] = emb_at(wemb, aemb, lat[l], ltk[l], d);
      Rt[l][dd] = emb_at(wemb, aemb, rat[l], rtk[l], d);
    }
    __syncthreads();
#pragma unroll 1
    for (int dd = 0; dd < 35; ++dd){
      float La[10], Rb[10];
#pragma unroll
      for (int i = 0; i < 10; ++i) La[i] = Lt[ty + 16 * i][dd];
#pragma unroll
      for (int j = 0; j < 10; ++j) Rb[j] = Rt[tx + 16 * j][dd];
#pragma unroll
      for (int i = 0; i < 10; ++i)
#pragma unroll
        for (int j = 0; j < 10; ++j)
          acc[i][j] = fmaf(La[i], Rb[j], acc[i][j]);
    }
    __syncthreads();
  }

  int ll = llen[b], rl = rlen[b];
#pragma unroll
  for (int i = 0; i < 10; ++i){
    bool lok = (ty + 16 * i) < ll;
#pragma unroll
    for (int j = 0; j < 10; ++j){
      if (!(lok && ((tx + 16 * j) < rl))) acc[i][j] = 0.f;
    }
  }
#pragma unroll
  for (int i = 0; i < 10; ++i){
    size_t rowb = ((size_t)bl * 160 + ty + 16 * i) * 160;
#pragma unroll
    for (int j = 0; j < 10; ++j) att[rowb + tx + 16 * j] = acc[i][j];
  }
  for (int jj = 0; jj < 10; ++jj){
    __syncthreads();
#pragma unroll
    for (int i = 0; i < 10; ++i) Tb[tx][ty + 16 * i] = acc[i][jj];
    __syncthreads();
    for (int i2 = tid; i2 < 16 * 160; i2 += 256){
      int rloc = i2 / 160, l = i2 - rloc * 160;
      attT[((size_t)bl * 160 + 16 * jj + rloc) * 160 + l] = Tb[rloc][l];
    }
  }
}

// ---------------- 2. per-row softmax+renorm, w, top-3, counter, |diff| ------
// Writes the counter-feature matrix directly as split bf16 (hi+lo planes),
// K-padded to 352 cols, for the MFMA conv-GEMM. One wave per (q, b) row.
__global__ __launch_bounds__(256) void proc_kernel(
    const float* __restrict__ attR,
    const int* __restrict__ ownLen, const int* __restrict__ kvLen,
    const int* __restrict__ ownTok, const int* __restrict__ ownAttr,
    const int* __restrict__ kvTok,  const int* __restrict__ kvAttr,
    const float* __restrict__ wemb, const float* __restrict__ aemb,
    unsigned short* __restrict__ outH, unsigned short* __restrict__ outL,
    int CB, int b0){
  int lane = threadIdx.x & 63;
  int wid = blockIdx.x * 4 + (threadIdx.x >> 6);
  int q  = wid / CB;
  int bl = wid - q * CB;
  int b  = b0 + bl;
  int nOwn = ownLen[b], nKv = kvLen[b];
  const float* __restrict__ row = attR + ((size_t)bl * 160 + q) * 160;
  int rr0 = lane, rr1 = lane + 64, rr2 = lane + 128;
  bool has2 = rr2 < 160;
  float a0 = row[rr0];
  float a1 = row[rr1];
  float a2 = has2 ? row[rr2] : 0.f;
  float v0 = (rr0 < nKv) ? a0 : -10.f;
  float v1 = (rr1 < nKv) ? a1 : -10.f;
  float v2 = has2 ? ((rr2 < nKv) ? a2 : -10.f) : -1e30f;
  float m = wmaxf(fmaxf(v0, fmaxf(v1, v2)));
  float e0 = expf(v0 - m);
  float e1 = expf(v1 - m);
  float e2 = has2 ? expf(v2 - m) : 0.f;
  float ssum = wsum(e0 + e1 + e2);
  float p0 = (rr0 < nKv) ? e0 / ssum : 0.f;
  float p1 = (rr1 < nKv) ? e1 / ssum : 0.f;
  float p2 = (has2 && rr2 < nKv) ? e2 / ssum : 0.f;
  float s2 = wsum(p0 + p1 + p2);
  float inv = 1.f / (s2 + 1e-13f);
  p0 *= inv; p1 *= inv; p2 *= inv;
  float sp  = wsum(p0 + p1 + p2);
  float sp2 = wsum(p0 * p0 + p1 * p1 + p2 * p2);
  float kf = (float)nKv;
  float mean = sp / kf;
  float w = (sp2 / kf - mean * mean) / fmaxf(mean, 0.001f);
  // top-3, JAX tie-break (lower index wins ties)
  unsigned long long key0 = (((unsigned long long)__float_as_uint(p0)) << 32) | (unsigned)(0xFFFFFFFFu - rr0);
  unsigned long long key1 = (((unsigned long long)__float_as_uint(p1)) << 32) | (unsigned)(0xFFFFFFFFu - rr1);
  unsigned long long key2 = has2 ? ((((unsigned long long)__float_as_uint(p2)) << 32) | (unsigned)(0xFFFFFFFFu - rr2)) : 0ull;
  float tv[3]; int ti[3];
#pragma unroll
  for (int kk = 0; kk < 3; ++kk){
    unsigned long long loc = key0 > key1 ? key0 : key1;
    loc = key2 > loc ? key2 : loc;
    unsigned long long g = wmax64(loc);
    tv[kk] = __uint_as_float((unsigned)(g >> 32));
    ti[kk] = (int)(0xFFFFFFFFu - (unsigned)g);
    if (key0 == g) key0 = 0ull;
    if (key1 == g) key1 = 0ull;
    if (key2 == g) key2 = 0ull;
  }
  float tsum = tv[0] + tv[1] + tv[2];
  float ad = 1.f / fmaxf(tsum, 0.001f);
  float c0 = tv[0] * ad, c1 = tv[1] * ad, c2 = tv[2] * ad;
  size_t rb = ((size_t)q * CB + bl) * 352;
  unsigned short* __restrict__ oh = outH + rb;
  unsigned short* __restrict__ ol = outL + rb;
  if (q < nOwn){
    int oa = ownAttr[q * NB + b],    ot = ownTok[q * NB + b];
    int a0i = kvAttr[ti[0] * NB + b], t0 = kvTok[ti[0] * NB + b];
    int a1i = kvAttr[ti[1] * NB + b], t1 = kvTok[ti[1] * NB + b];
    int a2i = kvAttr[ti[2] * NB + b], t2 = kvTok[ti[2] * NB + b];
    for (int d = lane; d < 352; d += 64){
      unsigned short hb = 0, lb = 0;
      if (d < 350){
        float ov = emb_at(wemb, aemb, oa, ot, d);
        float k0 = emb_at(wemb, aemb, a0i, t0, d);
        float k1 = emb_at(wemb, aemb, a1i, t1, d);
        float k2 = emb_at(wemb, aemb, a2i, t2, d);
        float cc = c0 * k0 + c1 * k1 + c2 * k2;
        float val = w * fabsf(ov - cc);
        hb = f2bf(val);
        lb = f2bf(val - bf2f(hb));  // Sterbenz: val-hi exact in fp32
      }
      oh[d] = hb; ol[d] = lb;
    }
  } else {
    for (int d = lane; d < 352; d += 64){ oh[d] = 0; ol[d] = 0; }
  }
}

// ---------------- 3. pack conv weights into split-bf16 Wcat (640 x 352) ----
// cols 0-99: w1 tap0 | 100-199: w2 tap0 | 200-299: w2 tap1
// 300-399: w3 tap0 | 400-499: w3 tap1 | 500-599: w3 tap2 | 600-639: zero pad
__global__ __launch_bounds__(256) void wcat_kernel(
    const float* __restrict__ w1, const float* __restrict__ w2,
    const float* __restrict__ w3,
    unsigned short* __restrict__ wcatH, unsigned short* __restrict__ wcatL){
  int idx = blockIdx.x * 256 + threadIdx.x;
  if (idx >= 640 * 352) return;
  int c = idx / 352, d = idx - c * 352;
  float v = 0.f;
  if (c < 600 && d < 350){
    if (c < 100) v = w1[c * 350 + d];
    else if (c < 300){
      int cc = c - 100; int j = cc / 100; int o = cc - j * 100;
      v = w2[(o * 350 + d) * 2 + j];
    } else {
      int cc = c - 300; int j = cc / 100; int o = cc - j * 100;
      v = w3[(o * 350 + d) * 3 + j];
    }
  }
  unsigned short hb = f2bf(v);
  wcatH[idx] = hb;
  wcatL[idx] = f2bf(v - bf2f(hb));
}

// ---------------- 4. P = A(Mx352) @ B^T(352x600) via split-bf16 MFMA -------
// A, B stored as hi/lo bf16 planes; D = Ah*Bh + Al*Bh + Ah*Bl (ll dropped,
// ~2^-18 relative). Tile 128x64, 4 waves (2x2), 16x16x32 MFMA, K=352.
// LDS rows padded to 40 shorts (80 B): b128 lane reads land 2-way (free).
__global__ __launch_bounds__(256) void gemm_mfma(
    const unsigned short* __restrict__ Agh, const unsigned short* __restrict__ Agl,
    const unsigned short* __restrict__ Bgh, const unsigned short* __restrict__ Bgl,
    float* __restrict__ P){
  __shared__ unsigned short Ah[128][40];
  __shared__ unsigned short Al[128][40];
  __shared__ unsigned short Bh[64][40];
  __shared__ unsigned short Bl[64][40];
  const int m0 = blockIdx.x * 128;
  const int n0 = blockIdx.y * 64;
  const int tid = threadIdx.x;
  const int lane = tid & 63;
  const int wid  = tid >> 6;
  const int wr = wid >> 1, wc = wid & 1;       // wave -> 64x32 sub-tile
  const int lrow = lane & 15, lkg = lane >> 4; // MFMA lane mapping

  // staging: 16B chunks; thread covers A rows {t>>2, t>>2+64} chunk t&3, B row t>>2
  const int srow = tid >> 2;
  const int sq   = tid & 3;
  const size_t Aoff0 = (size_t)(m0 + srow)      * 352 + sq * 8;
  const size_t Aoff1 = (size_t)(m0 + srow + 64) * 352 + sq * 8;
  const size_t Boff  = (size_t)(n0 + srow)      * 352 + sq * 8;

  f32x4 acc[4][2];
#pragma unroll
  for (int i = 0; i < 4; ++i)
#pragma unroll
    for (int j = 0; j < 2; ++j) acc[i][j] = (f32x4){0.f, 0.f, 0.f, 0.f};

  // prefetch K-step 0
  u16x8 rah0 = *(const u16x8*)(Agh + Aoff0);
  u16x8 rah1 = *(const u16x8*)(Agh + Aoff1);
  u16x8 ral0 = *(const u16x8*)(Agl + Aoff0);
  u16x8 ral1 = *(const u16x8*)(Agl + Aoff1);
  u16x8 rbh  = *(const u16x8*)(Bgh + Boff);
  u16x8 rbl  = *(const u16x8*)(Bgl + Boff);

  for (int ks = 0; ks < 11; ++ks){
    __syncthreads();   // previous compute done; LDS reusable
    *(u16x8*)&Ah[srow][sq * 8]      = rah0;
    *(u16x8*)&Ah[srow + 64][sq * 8] = rah1;
    *(u16x8*)&Al[srow][sq * 8]      = ral0;
    *(u16x8*)&Al[srow + 64][sq * 8] = ral1;
    *(u16x8*)&Bh[srow][sq * 8]      = rbh;
    *(u16x8*)&Bl[srow][sq * 8]      = rbl;
    if (ks < 10){
      int k1 = (ks + 1) * 32;
      rah0 = *(const u16x8*)(Agh + Aoff0 + k1);
      rah1 = *(const u16x8*)(Agh + Aoff1 + k1);
      ral0 = *(const u16x8*)(Agl + Aoff0 + k1);
      ral1 = *(const u16x8*)(Agl + Aoff1 + k1);
      rbh  = *(const u16x8*)(Bgh + Boff + k1);
      rbl  = *(const u16x8*)(Bgl + Boff + k1);
    }
    __syncthreads();

    bf16x8 fah[4], fal[4], fbh[2], fbl[2];
#pragma unroll
    for (int mi = 0; mi < 4; ++mi){
      int r = wr * 64 + mi * 16 + lrow;
      fah[mi] = *(const bf16x8*)&Ah[r][lkg * 8];
      fal[mi] = *(const bf16x8*)&Al[r][lkg * 8];
    }
#pragma unroll
    for (int nj = 0; nj < 2; ++nj){
      int r = wc * 32 + nj * 16 + lrow;
      fbh[nj] = *(const bf16x8*)&Bh[r][lkg * 8];
      fbl[nj] = *(const bf16x8*)&Bl[r][lkg * 8];
    }
#pragma unroll
    for (int mi = 0; mi < 4; ++mi)
#pragma unroll
      for (int nj = 0; nj < 2; ++nj){
        acc[mi][nj] = __builtin_amdgcn_mfma_f32_16x16x32_bf16(fah[mi], fbh[nj], acc[mi][nj], 0, 0, 0);
        acc[mi][nj] = __builtin_amdgcn_mfma_f32_16x16x32_bf16(fal[mi], fbh[nj], acc[mi][nj], 0, 0, 0);
        acc[mi][nj] = __builtin_amdgcn_mfma_f32_16x16x32_bf16(fah[mi], fbl[nj], acc[mi][nj], 0, 0, 0);
      }
  }

  // C/D layout (m89-verified): col = lane&15, row = (lane>>4)*4 + reg
#pragma unroll
  for (int mi = 0; mi < 4; ++mi){
#pragma unroll
    for (int nj = 0; nj < 2; ++nj){
      int col = n0 + wc * 32 + nj * 16 + lrow;
      if (col < 600){
        size_t rowb = (size_t)(m0 + wr * 64 + mi * 16 + lkg * 4) * 600 + col;
#pragma unroll
        for (int r = 0; r < 4; ++r)
          P[rowb + (size_t)r * 600] = acc[mi][nj][r];
      }
    }
  }
}

// ---------------- 5. shift-combine + bias + relu + masked max over t --------
__global__ __launch_bounds__(320) void combine_kernel(
    const float* __restrict__ P, const int* __restrict__ len,
    const float* __restrict__ b1, const float* __restrict__ b2,
    const float* __restrict__ b3, float* __restrict__ feats,
    int sideoff, int CB, int b0){
  int bl = blockIdx.x;
  int b = b0 + bl;
  int c = threadIdx.x;
  if (c >= 300) return;
  int n = len[b];
  float vmax = -1e30f;
  if (c < 100){
    float bias = b1[c];
    for (int t = 0; t < n; ++t){
      float v = P[(size_t)(t * CB + bl) * 600 + c] + bias;
      vmax = fmaxf(vmax, fmaxf(v, 0.f));
    }
  } else if (c < 200){
    int o = c - 100;
    float bias = b2[o];
    for (int t = 0; t + 1 < n; ++t){
      float v = P[(size_t)(t * CB + bl) * 600 + 100 + o]
              + P[(size_t)((t + 1) * CB + bl) * 600 + 200 + o] + bias;
      vmax = fmaxf(vmax, fmaxf(v, 0.f));
    }
  } else {
    int o = c - 200;
    float bias = b3[o];
    for (int t = 0; t + 2 < n; ++t){
      float v = P[(size_t)(t * CB + bl) * 600 + 300 + o]
              + P[(size_t)((t + 1) * CB + bl) * 600 + 400 + o]
              + P[(size_t)((t + 2) * CB + bl) * 600 + 500 + o] + bias;
      vmax = fmaxf(vmax, fmaxf(v, 0.f));
    }
  }
  feats[(size_t)b * 600 + sideoff + c] = vmax;
}

// ---------------- 6. dense head ---------------------------------------------
__global__ __launch_bounds__(64) void dense_kernel(
    const float* __restrict__ feats,
    const float* __restrict__ w1, const float* __restrict__ b1,
    const float* __restrict__ w2, const float* __restrict__ b2,
    float* __restrict__ out){
  __shared__ float fs[600];
  __shared__ float hs[60];
  int b = blockIdx.x, tid = threadIdx.x;
  for (int i = tid; i < 600; i += 64) fs[i] = feats[(size_t)b * 600 + i];
  __syncthreads();
  if (tid < 60){
    float s = b1[tid];
    for (int d = 0; d < 600; ++d) s = fmaf(fs[d], w1[d * 60 + tid], s);
    hs[tid] = fmaxf(s, 0.f);
  }
  __syncthreads();
  if (tid < 2){
    float s = b2[tid];
    for (int j = 0; j < 60; ++j) s = fmaf(hs[j], w2[j * 2 + tid], s);
    out[b * 2 + tid] = s;
  }
}

// ---------------- launch ----------------------------------------------------
extern "C" void kernel_launch(void* const* d_in, const int* in_sizes, int n_in,
                              void* d_out, int out_size, void* d_ws, size_t ws_size,
                              hipStream_t stream){
  const int*   l_tok = (const int*)d_in[0];
  const int*   l_att = (const int*)d_in[1];
  const int*   l_len = (const int*)d_in[2];
  const int*   r_tok = (const int*)d_in[3];
  const int*   r_att = (const int*)d_in[4];
  const int*   r_len = (const int*)d_in[5];
  const float* wemb  = (const float*)d_in[6];
  const float* aemb  = (const float*)d_in[7];
  const float* cw1   = (const float*)d_in[8];
  const float* cb1   = (const float*)d_in[9];
  const float* cw2   = (const float*)d_in[10];
  const float* cb2   = (const float*)d_in[11];
  const float* cw3   = (const float*)d_in[12];
  const float* cb3   = (const float*)d_in[13];
  const float* dw1   = (const float*)d_in[14];
  const float* db1   = (const float*)d_in[15];
  const float* dw2   = (const float*)d_in[16];
  const float* db2   = (const float*)d_in[17];
  float* out = (float*)d_out;

  // Workspace (bytes per batch): att+attT 2*102400, lc/rc hi+lo 4*112640,
  // P 384000  => 1,039,360 B/batch.  Persistent: feats 1,228,800 +
  // wcatH/L 2*450,560 = 2,129,920 B.  CB multiple of 4 (128 | 160*CB).
  int CB = 512;
  while (CB > 4){
    size_t need = (size_t)CB * 1039360 + 2129920 + 4096;
    if (need <= ws_size) break;
    CB >>= 1;
  }

  char* p = (char*)d_ws;
  float* feats = (float*)p;                  p += 1228800;
  unsigned short* wcatH = (unsigned short*)p; p += 450560;
  unsigned short* wcatL = (unsigned short*)p; p += 450560;
  float* att  = (float*)p;                   p += (size_t)CB * 102400;
  float* attT = (float*)p;                   p += (size_t)CB * 102400;
  unsigned short* lcH = (unsigned short*)p;  p += (size_t)CB * 112640;
  unsigned short* lcL = (unsigned short*)p;  p += (size_t)CB * 112640;
  unsigned short* rcH = (unsigned short*)p;  p += (size_t)CB * 112640;
  unsigned short* rcL = (unsigned short*)p;  p += (size_t)CB * 112640;
  float* P = (float*)p;

  wcat_kernel<<<880, 256, 0, stream>>>(cw1, cw2, cw3, wcatH, wcatL);

  int nch = NB / CB;
  dim3 gP(CB * 160 / 128, 10);
  for (int c = 0; c < nch; ++c){
    int b0 = c * CB;
    att_gemm<<<CB, 256, 0, stream>>>(l_tok, l_att, r_tok, r_att, wemb, aemb,
                                     l_len, r_len, att, attT, b0);
    proc_kernel<<<CB * 40, 256, 0, stream>>>(att,  l_len, r_len,
                                             l_tok, l_att, r_tok, r_att,
                                             wemb, aemb, lcH, lcL, CB, b0);
    proc_kernel<<<CB * 40, 256, 0, stream>>>(attT, r_len, l_len,
                                             r_tok, r_att, l_tok, l_att,
                                             wemb, aemb, rcH, rcL, CB, b0);
    gemm_mfma<<<gP, 256, 0, stream>>>(lcH, lcL, wcatH, wcatL, P);
    combine_kernel<<<CB, 320, 0, stream>>>(P, l_len, cb1, cb2, cb3, feats, 0,   CB, b0);
    gemm_mfma<<<gP, 256, 0, stream>>>(rcH, rcL, wcatH, wcatL, P);
    combine_kernel<<<CB, 320, 0, stream>>>(P, r_len, cb1, cb2, cb3, feats, 300, CB, b0);
  }
  dense_kernel<<<NB, 64, 0, stream>>>(feats, dw1, db1, dw2, db2, out);
}